// Round 1
// 323.094 us; speedup vs baseline: 1.0058x; 1.0058x over previous
//
#include <hip/hip_runtime.h>
#include <hip/hip_bf16.h>
#include <stdint.h>

#define HID   2048
#define SLEN  2048
#define NB    2
#define NHEADS 32
#define NKVH   8
#define HDIM   64
#define KVW    512   // NKVH*HDIM

typedef __bf16 bf16_t;
typedef __bf16 bf16x4 __attribute__((ext_vector_type(4)));
typedef __bf16 bf16x8 __attribute__((ext_vector_type(8)));
typedef float  f32x4  __attribute__((ext_vector_type(4)));

__device__ __forceinline__ f32x4 mfma16(bf16x8 a, bf16x8 b, f32x4 c) {
  return __builtin_amdgcn_mfma_f32_16x16x32_bf16(a, b, c, 0, 0, 0);
}

__device__ __forceinline__ void gl2lds16(const bf16_t* g, bf16_t* l) {
  __builtin_amdgcn_global_load_lds(
      (const __attribute__((address_space(1))) void*)g,
      (__attribute__((address_space(3))) void*)l,
      16, 0, 0);
}

__device__ __forceinline__ float fast_exp2(float x) {
#if __has_builtin(__builtin_amdgcn_exp2f)
  return __builtin_amdgcn_exp2f(x);
#else
  return __expf(x * 0.69314718f);
#endif
}

__device__ __forceinline__ bf16x8 ld8(const bf16_t* p) {
  return *(const bf16x8*)p;
}
__device__ __forceinline__ bf16x8 ld8(const float* p) {
  f32x4 a = *(const f32x4*)p;
  f32x4 b = *(const f32x4*)(p + 4);
  bf16x8 r;
  r[0] = (bf16_t)a[0]; r[1] = (bf16_t)a[1]; r[2] = (bf16_t)a[2]; r[3] = (bf16_t)a[3];
  r[4] = (bf16_t)b[0]; r[5] = (bf16_t)b[1]; r[6] = (bf16_t)b[2]; r[7] = (bf16_t)b[3];
  return r;
}

__device__ __forceinline__ void st_c(bf16_t* p, float v) { *p = (bf16_t)v; }
__device__ __forceinline__ void st_c(float*  p, float v) { *p = v; }

// ---------------- fp32 -> bf16 convert pass (Path A prologue) ---------------
__global__ __launch_bounds__(256) void cvt_kernel(
    const float* __restrict__ x,  const float* __restrict__ wq,
    const float* __restrict__ wk, const float* __restrict__ wv,
    const float* __restrict__ wo,
    bf16_t* xb, bf16_t* wqb, bf16_t* wkb, bf16_t* wvb, bf16_t* wob)
{
  const float* s; bf16_t* d; size_t n;
  switch (blockIdx.y) {
    case 0:  s = x;  d = xb;  n = (size_t)NB * SLEN * HID; break;
    case 1:  s = wq; d = wqb; n = (size_t)HID * HID; break;
    case 2:  s = wk; d = wkb; n = (size_t)KVW * HID; break;
    case 3:  s = wv; d = wvb; n = (size_t)KVW * HID; break;
    default: s = wo; d = wob; n = (size_t)HID * HID; break;
  }
  const size_t stride = (size_t)gridDim.x * 256 * 8;
  for (size_t i = ((size_t)blockIdx.x * 256 + threadIdx.x) * 8; i < n; i += stride)
    *(bf16x8*)(d + i) = ld8(s + i);
}

// ====================== 256x256 8-phase GEMM (T2+T3+T4+T5) ==================
// BM=BN=256, BK=64, 512 threads = 8 waves (2M x 4N), per-wave C = 128x64.
// LDS 128 KiB: 2 buffers x {A 256x64, B 256x64} bf16, halves of 128 rows.
// Swizzle: logical (row r, 16B-group g) stored at byte r*128 + ((g^(r&7))*16).
// global_load_lds dest is linear; the XOR is applied to the GLOBAL source
// (rule #21: linear dest + inverse-swizzled source + swizzled read).
// Per 2-K-tile iteration: 8 phases, one half-tile staged per phase:
//   p0:A0(t+1) p1:A1(t+1) p2:B0(t+2) p3:B1(t+2) p4:A0(t+2) p5:A1(t+2)
//   p6:B0(t+3) p7:B1(t+3)
// vmcnt(4) only at end of p3 and p7 (in-order vmcnt => the 4 newest loads,
// B halves of the NEXT tile-pair, may stay in flight; everything the next
// phase consumes is guaranteed landed). Never vmcnt(0) mid-loop.

__device__ __forceinline__ bf16x8 ldfrag(const bf16_t* __restrict__ Lh, int r, int g) {
  return *(const bf16x8*)(Lh + r * 64 + ((g ^ (r & 7)) << 3));
}

template <int Q>
__device__ __forceinline__ void mfma_quad(const bf16x8 (&af)[2][2],
                                          const bf16x8 (&bfr)[4][2],
                                          f32x4 (&acc)[8][4]) {
#pragma unroll
  for (int ks = 0; ks < 2; ++ks)
#pragma unroll
    for (int i = 0; i < 2; ++i)
#pragma unroll
      for (int ni = 0; ni < 4; ++ni)
        acc[2 * Q + i][ni] = mfma16(af[i][ks], bfr[ni][ks], acc[2 * Q + i][ni]);
}

__device__ __forceinline__ void phase_barrier() {
  __builtin_amdgcn_s_barrier();
  asm volatile("" ::: "memory");   // keep loads from hoisting above the barrier
}

__device__ __forceinline__ void gemm256_core(
    const bf16_t* __restrict__ Ag,   // A panel base (row brow), row stride HID
    const bf16_t* __restrict__ Bg,   // B panel base (row bcol), row stride HID
    bf16_t* __restrict__ lds, f32x4 (&acc)[8][4])
{
  const int tid  = threadIdx.x;
  const int lane = tid & 63;
  const int w    = tid >> 6;
  const int fr   = lane & 15;
  const int quad = lane >> 4;
  const int wr   = w >> 2;        // 0..1 (M)
  const int wc   = w & 3;         // 0..3 (N)
  const int rbB  = (wc & 1) * 64;

  bf16_t* A0 = lds;
  bf16_t* B0 = lds + 16384;
  bf16_t* A1 = lds + 32768;
  bf16_t* B1 = lds + 49152;
  const bf16_t* Ar0 = A0 + wr * 8192;
  const bf16_t* Br0 = B0 + (wc >> 1) * 8192;
  const bf16_t* Ar1 = A1 + wr * 8192;
  const bf16_t* Br1 = B1 + (wc >> 1) * 8192;

  const f32x4 z4 = {0.f, 0.f, 0.f, 0.f};
#pragma unroll
  for (int i = 0; i < 8; ++i)
#pragma unroll
    for (int j = 0; j < 4; ++j) acc[i][j] = z4;

  auto STAGE = [&](const bf16_t* __restrict__ Gp, bf16_t* __restrict__ Lh) {
#pragma unroll
    for (int j = 0; j < 2; ++j) {
      const int s = j * 512 + tid;
      const int r = s >> 3;
      const int g = (s & 7) ^ (r & 7);      // inverse swizzle on global source
      gl2lds16(Gp + (size_t)r * HID + g * 8, Lh + s * 8);
    }
  };

  // Prologue: B(0), A(0), B(1)  (A(1) staged at p0/p1 of iteration 0)
  STAGE(Bg,                  B0);
  STAGE(Bg + 128 * HID,      B0 + 8192);
  STAGE(Ag,                  A0);
  STAGE(Ag + 128 * HID,      A0 + 8192);
  STAGE(Bg + 64,             B1);
  STAGE(Bg + 128 * HID + 64, B1 + 8192);
  asm volatile("s_waitcnt vmcnt(4)" ::: "memory");   // buf0 fully landed
  phase_barrier();

  bf16x8 bfr[4][2], af[2][2];

#pragma unroll 1
  for (int it = 0; it < 16; ++it) {
    const bool more = (it < 15);
    const size_t k1 = (size_t)(2 * it + 1) * 64;
    const size_t k2 = (size_t)(2 * it + 2) * 64;
    const size_t k3 = (size_t)(2 * it + 3) * 64;

    // ---- phase 0: tile t (buf0), quadrant 0; stage A.h0(t+1) -> buf1
#pragma unroll
    for (int ni = 0; ni < 4; ++ni)
#pragma unroll
      for (int ks = 0; ks < 2; ++ks)
        bfr[ni][ks] = ldfrag(Br0, rbB + ni * 16 + fr, ks * 4 + quad);
#pragma unroll
    for (int i = 0; i < 2; ++i)
#pragma unroll
      for (int ks = 0; ks < 2; ++ks)
        af[i][ks] = ldfrag(Ar0, i * 16 + fr, ks * 4 + quad);
    STAGE(Ag + k1, A1);
    phase_barrier();
    asm volatile("s_waitcnt lgkmcnt(0)" ::: "memory");
    __builtin_amdgcn_s_setprio(1);
    mfma_quad<0>(af, bfr, acc);
    __builtin_amdgcn_s_setprio(0);
    phase_barrier();

    // ---- phase 1: q=1; stage A.h1(t+1)
#pragma unroll
    for (int i = 0; i < 2; ++i)
#pragma unroll
      for (int ks = 0; ks < 2; ++ks)
        af[i][ks] = ldfrag(Ar0, 32 + i * 16 + fr, ks * 4 + quad);
    STAGE(Ag + 128 * HID + k1, A1 + 8192);
    phase_barrier();
    asm volatile("s_waitcnt lgkmcnt(0)" ::: "memory");
    __builtin_amdgcn_s_setprio(1);
    mfma_quad<1>(af, bfr, acc);
    __builtin_amdgcn_s_setprio(0);
    phase_barrier();

    // ---- phase 2: q=2; stage B.h0(t+2) (B(t) slots freed after p0)
#pragma unroll
    for (int i = 0; i < 2; ++i)
#pragma unroll
      for (int ks = 0; ks < 2; ++ks)
        af[i][ks] = ldfrag(Ar0, 64 + i * 16 + fr, ks * 4 + quad);
    if (more) STAGE(Bg + k2, B0);
    phase_barrier();
    asm volatile("s_waitcnt lgkmcnt(0)" ::: "memory");
    __builtin_amdgcn_s_setprio(1);
    mfma_quad<2>(af, bfr, acc);
    __builtin_amdgcn_s_setprio(0);
    phase_barrier();

    // ---- phase 3: q=3; stage B.h1(t+2); K-tile boundary vmcnt
#pragma unroll
    for (int i = 0; i < 2; ++i)
#pragma unroll
      for (int ks = 0; ks < 2; ++ks)
        af[i][ks] = ldfrag(Ar0, 96 + i * 16 + fr, ks * 4 + quad);
    if (more) STAGE(Bg + 128 * HID + k2, B0 + 8192);
    phase_barrier();
    asm volatile("s_waitcnt lgkmcnt(0)" ::: "memory");
    __builtin_amdgcn_s_setprio(1);
    mfma_quad<3>(af, bfr, acc);
    __builtin_amdgcn_s_setprio(0);
    if (more) { asm volatile("s_waitcnt vmcnt(4)" ::: "memory"); }
    else      { asm volatile("s_waitcnt vmcnt(0)" ::: "memory"); }
    phase_barrier();

    // ---- phase 4: tile t+1 (buf1), q=0; stage A.h0(t+2) (A(t) freed after p3)
#pragma unroll
    for (int ni = 0; ni < 4; ++ni)
#pragma unroll
      for (int ks = 0; ks < 2; ++ks)
        bfr[ni][ks] = ldfrag(Br1, rbB + ni * 16 + fr, ks * 4 + quad);
#pragma unroll
    for (int i = 0; i < 2; ++i)
#pragma unroll
      for (int ks = 0; ks < 2; ++ks)
        af[i][ks] = ldfrag(Ar1, i * 16 + fr, ks * 4 + quad);
    if (more) STAGE(Ag + k2, A0);
    phase_barrier();
    asm volatile("s_waitcnt lgkmcnt(0)" ::: "memory");
    __builtin_amdgcn_s_setprio(1);
    mfma_quad<0>(af, bfr, acc);
    __builtin_amdgcn_s_setprio(0);
    phase_barrier();

    // ---- phase 5: q=1; stage A.h1(t+2)
#pragma unroll
    for (int i = 0; i < 2; ++i)
#pragma unroll
      for (int ks = 0; ks < 2; ++ks)
        af[i][ks] = ldfrag(Ar1, 32 + i * 16 + fr, ks * 4 + quad);
    if (more) STAGE(Ag + 128 * HID + k2, A0 + 8192);
    phase_barrier();
    asm volatile("s_waitcnt lgkmcnt(0)" ::: "memory");
    __builtin_amdgcn_s_setprio(1);
    mfma_quad<1>(af, bfr, acc);
    __builtin_amdgcn_s_setprio(0);
    phase_barrier();

    // ---- phase 6: q=2; stage B.h0(t+3) (B(t+1) freed after p4)
#pragma unroll
    for (int i = 0; i < 2; ++i)
#pragma unroll
      for (int ks = 0; ks < 2; ++ks)
        af[i][ks] = ldfrag(Ar1, 64 + i * 16 + fr, ks * 4 + quad);
    if (more) STAGE(Bg + k3, B1);
    phase_barrier();
    asm volatile("s_waitcnt lgkmcnt(0)" ::: "memory");
    __builtin_amdgcn_s_setprio(1);
    mfma_quad<2>(af, bfr, acc);
    __builtin_amdgcn_s_setprio(0);
    phase_barrier();

    // ---- phase 7: q=3; stage B.h1(t+3); iteration boundary vmcnt
#pragma unroll
    for (int i = 0; i < 2; ++i)
#pragma unroll
      for (int ks = 0; ks < 2; ++ks)
        af[i][ks] = ldfrag(Ar1, 96 + i * 16 + fr, ks * 4 + quad);
    if (more) STAGE(Bg + 128 * HID + k3, B1 + 8192);
    phase_barrier();
    asm volatile("s_waitcnt lgkmcnt(0)" ::: "memory");
    __builtin_amdgcn_s_setprio(1);
    mfma_quad<3>(af, bfr, acc);
    __builtin_amdgcn_s_setprio(0);
    if (more) { asm volatile("s_waitcnt vmcnt(4)" ::: "memory"); }
    phase_barrier();
  }
}

// QKV as one fused GEMM over Wcat = [Wq|Wk|Wv] (3072 x 2048, contiguous in ws).
// cb 0..7: Q cols; cb 8..9: K cols; cb 10..11: V cols (written transposed).
__global__ __launch_bounds__(512, 2) void qkv8_kernel(
    const bf16_t* __restrict__ xb, const bf16_t* __restrict__ Wcat,
    const float* __restrict__ bcat,
    bf16_t* __restrict__ Qb, bf16_t* __restrict__ Kb, bf16_t* __restrict__ VbT)
{
  __shared__ __align__(16) bf16_t lds[65536];
  const int cb = blockIdx.x;   // 0..11
  const int mb = blockIdx.y;   // 0..15
  f32x4 acc[8][4];
  gemm256_core(xb + (size_t)mb * 256 * HID, Wcat + (size_t)cb * 256 * HID, lds, acc);

  const int tid = threadIdx.x, lane = tid & 63, w = tid >> 6;
  const int fr = lane & 15, quad = lane >> 4, wr = w >> 2, wc = w & 3;
#pragma unroll
  for (int ni = 0; ni < 4; ++ni) {
    const int gcol = cb * 256 + wc * 64 + ni * 16 + fr;
    const float bz = bcat[gcol];
#pragma unroll
    for (int mi = 0; mi < 8; ++mi) {
      const int grow = mb * 256 + wr * 128 + mi * 16 + quad * 4;
      if (cb < 8) {
#pragma unroll
        for (int r = 0; r < 4; ++r)
          Qb[(size_t)(grow + r) * HID + gcol] = (bf16_t)(acc[mi][ni][r] + bz);
      } else if (cb < 10) {
        const int kc = gcol - 2048;
#pragma unroll
        for (int r = 0; r < 4; ++r)
          Kb[(size_t)(grow + r) * KVW + kc] = (bf16_t)(acc[mi][ni][r] + bz);
      } else {
        const int vc = gcol - 2560;       // 0..511
        const int b = grow >> 11, s = grow & 2047;
        bf16x4 pk;
#pragma unroll
        for (int r = 0; r < 4; ++r) pk[r] = (bf16_t)(acc[mi][ni][r] + bz);
        *(bf16x4*)&VbT[((size_t)(b * NKVH + (vc >> 6)) * HDIM + (vc & 63)) * SLEN + s] = pk;
      }
    }
  }
}

__global__ __launch_bounds__(512, 2) void oproj8_kernel(
    const bf16_t* __restrict__ A, const bf16_t* __restrict__ Wob,
    const float* __restrict__ bo, float* __restrict__ out)
{
  __shared__ __align__(16) bf16_t lds[65536];
  const int cb = blockIdx.x;   // 0..7
  const int mb = blockIdx.y;   // 0..15
  f32x4 acc[8][4];
  gemm256_core(A + (size_t)mb * 256 * HID, Wob + (size_t)cb * 256 * HID, lds, acc);

  const int tid = threadIdx.x, lane = tid & 63, w = tid >> 6;
  const int fr = lane & 15, quad = lane >> 4, wr = w >> 2, wc = w & 3;
#pragma unroll
  for (int ni = 0; ni < 4; ++ni) {
    const int gcol = cb * 256 + wc * 64 + ni * 16 + fr;
    const float bz = bo[gcol];
#pragma unroll
    for (int mi = 0; mi < 8; ++mi) {
      const int grow = mb * 256 + wr * 128 + mi * 16 + quad * 4;
#pragma unroll
      for (int r = 0; r < 4; ++r)
        out[(size_t)(grow + r) * HID + gcol] = acc[mi][ni][r] + bz;
    }
  }
}

// ---------------- Path B (fallback): fp32-source GEMM -----------------------
template <typename AT, typename CT>
__device__ __forceinline__ void gemm128_tile(
    const AT* __restrict__ Ap, int lda,
    const float* __restrict__ Wp, int ldw,
    const float* __restrict__ biasp,
    CT* __restrict__ Cp, int ldc,
    int K)
{
  __shared__ __align__(16) bf16_t Al[128 * 32];
  __shared__ __align__(16) bf16_t Bl[128 * 32];

  const int tid  = threadIdx.x;
  const int lane = tid & 63;
  const int w    = tid >> 6;
  const int fr   = lane & 15;
  const int quad = lane >> 4;
  const int wm   = (w >> 1) * 64;
  const int wn   = (w & 1) * 64;

  const f32x4 z4 = {0.f, 0.f, 0.f, 0.f};
  f32x4 acc[4][4];
  for (int i = 0; i < 4; ++i)
    for (int j = 0; j < 4; ++j) acc[i][j] = z4;

  const int c0    = w * 2;
  const int srow0 = lane >> 2;
  const int skc   = (lane & 3) * 8;

  for (int k0 = 0; k0 < K; k0 += 32) {
    bf16x8 av[2], bv[2];
    for (int t = 0; t < 2; ++t) {
      const int r = (c0 + t) * 16 + srow0;
      av[t] = ld8(Ap + (size_t)r * lda + k0 + skc);
      bv[t] = ld8(Wp + (size_t)r * ldw + k0 + skc);
    }
    for (int t = 0; t < 2; ++t) {
      const int c = c0 + t;
      *(bf16x8*)&Al[c * 512 + lane * 8] = av[t];
      *(bf16x8*)&Bl[c * 512 + lane * 8] = bv[t];
    }
    __syncthreads();
    bf16x8 af[4], bfr[4];
    for (int mi = 0; mi < 4; ++mi)
      af[mi] = *(const bf16x8*)&Al[(wm + mi * 16 + fr) * 32 + quad * 8];
    for (int ni = 0; ni < 4; ++ni)
      bfr[ni] = *(const bf16x8*)&Bl[(wn + ni * 16 + fr) * 32 + quad * 8];
    for (int mi = 0; mi < 4; ++mi)
      for (int ni = 0; ni < 4; ++ni)
        acc[mi][ni] = mfma16(af[mi], bfr[ni], acc[mi][ni]);
    __syncthreads();
  }

  for (int ni = 0; ni < 4; ++ni) {
    const int col = wn + ni * 16 + fr;
    const float bz = biasp[col];
    for (int mi = 0; mi < 4; ++mi) {
      const int r0 = wm + mi * 16 + quad * 4;
      for (int r = 0; r < 4; ++r)
        st_c(Cp + (size_t)(r0 + r) * ldc + col, acc[mi][ni][r] + bz);
    }
  }
}

__global__ __launch_bounds__(256) void qkv_kernel(
    const float* __restrict__ x,
    const float* __restrict__ Wq, const float* __restrict__ bq,
    const float* __restrict__ Wk, const float* __restrict__ bk,
    const float* __restrict__ Wv, const float* __restrict__ bv,
    bf16_t* Qb, bf16_t* Kb, bf16_t* Vb)
{
  const int nb = blockIdx.x;
  const int mb = blockIdx.y;
  const float* W; const float* bias; bf16_t* C; int ldc;
  if (nb < 16)      { W = Wq + (size_t)nb * 128 * HID;  bias = bq + nb * 128;
                      C = Qb + nb * 128; ldc = HID; }
  else if (nb < 20) { const int j = nb - 16;
                      W = Wk + (size_t)j * 128 * HID;   bias = bk + j * 128;
                      C = Kb + j * 128; ldc = KVW; }
  else              { const int j = nb - 20;
                      W = Wv + (size_t)j * 128 * HID;   bias = bv + j * 128;
                      C = Vb + j * 128; ldc = KVW; }
  gemm128_tile<float, bf16_t>(x + (size_t)mb * 128 * HID, HID, W, HID, bias,
                              C + (size_t)mb * 128 * ldc, ldc, HID);
}

__global__ __launch_bounds__(256) void oproj_kernel(
    const bf16_t* __restrict__ A, const float* __restrict__ Wo,
    const float* __restrict__ bo, float* out)
{
  const int nb = blockIdx.x, mb = blockIdx.y;
  gemm128_tile<bf16_t, float>(A + (size_t)mb * 128 * HID, HID,
                              Wo + (size_t)nb * 128 * HID, HID,
                              bo + nb * 128,
                              out + (size_t)mb * 128 * HID + nb * 128, HID, HID);
}

__global__ __launch_bounds__(256) void vtrans_kernel(
    const bf16_t* __restrict__ Vb, bf16_t* __restrict__ VbT)
{
  __shared__ bf16_t T[64][72];
  const int st = blockIdx.x, kvh = blockIdx.y, b = blockIdx.z;
  const int tid = threadIdx.x;
  {
    const int row = tid >> 2;
    const int c16 = (tid & 3) * 16;
    const bf16_t* src =
        Vb + ((size_t)b * SLEN + st * 64 + row) * KVW + kvh * HDIM + c16;
    *(bf16x8*)&T[row][c16]     = *(const bf16x8*)(src);
    *(bf16x8*)&T[row][c16 + 8] = *(const bf16x8*)(src + 8);
  }
  __syncthreads();
  {
    const int d  = tid >> 2;
    const int sc = (tid & 3) * 16;
    bf16_t tmp[16];
    for (int j = 0; j < 16; ++j) tmp[j] = T[sc + j][d];
    bf16_t* dst = VbT + ((size_t)(b * NKVH + kvh) * HDIM + d) * SLEN + st * 64 + sc;
    *(bf16x8*)dst       = *(bf16x8*)&tmp[0];
    *(bf16x8*)(dst + 8) = *(bf16x8*)&tmp[8];
  }
}

// ---------------- Flash attention (unchanged) -------------------------------
__global__ __launch_bounds__(256) void attn_kernel(
    const bf16_t* Q, const bf16_t* __restrict__ Kg,
    const bf16_t* __restrict__ VT, bf16_t* O)
{
  const int pid = blockIdx.x;        // 0..7
  const int h   = blockIdx.y;
  const int b   = blockIdx.z;
  const int kvh = h >> 2;

  const int tid  = threadIdx.x;
  const int lane = tid & 63;
  const int w    = tid >> 6;
  const int fr   = lane & 15;
  const int quad = lane >> 4;

  const int PS  = 72;
  const int VTS = 136;
  __shared__ __align__(16) bf16_t KL[8192];
  __shared__ __align__(16) bf16_t PP[128 * 72];
  __shared__ __align__(16) bf16_t Vt[64 * 136];

  const size_t qbase = (size_t)b * SLEN;
  const bf16_t* VTh = VT + (size_t)(b * NKVH + kvh) * HDIM * SLEN;

  bf16x8 ones8;
  {
    const bf16_t o1 = (bf16_t)(fr == 0 ? 1.0f : 0.0f);
    for (int j = 0; j < 8; ++j) ones8[j] = o1;
  }

  for (int half = 0; half < 2; ++half) {
    const int qt = half ? (15 - pid) : pid;
    const int q0 = qt * 128;

    bf16x8 qf[2][2];
    for (int qi = 0; qi < 2; ++qi)
      for (int ks = 0; ks < 2; ++ks) {
        const size_t qrow = qbase + q0 + w * 32 + qi * 16 + fr;
        qf[qi][ks] = *(const bf16x8*)&Q[qrow * HID + h * HDIM + ks * 32 + quad * 8];
      }

    const f32x4 z4 = {0.f, 0.f, 0.f, 0.f};
    f32x4 o_acc[2][4];
    f32x4 o_l[2];
    for (int qi = 0; qi < 2; ++qi) {
      o_l[qi] = z4;
      for (int di = 0; di < 4; ++di) o_acc[qi][di] = z4;
    }

    for (int kt = 0; kt <= qt; ++kt) {
      const size_t krow0 = qbase + kt * 128;

      for (int t = 0; t < 4; ++t) {
        const int c  = w * 4 + t;
        const int hf = c >> 3;
        const int r  = (c & 7) * 16 + (lane >> 2);
        const int dk = hf * 32 + (lane & 3) * 8;
        gl2lds16(&Kg[(krow0 + r) * KVW + kvh * HDIM + dk], &KL[c * 512 + lane * 8]);
      }
      {
        const int d  = tid >> 2;
        const int kc = (tid & 3) * 32;
        const bf16_t* src = VTh + (size_t)d * SLEN + kt * 128 + kc;
        bf16x8 v0 = *(const bf16x8*)(src);
        bf16x8 v1 = *(const bf16x8*)(src + 8);
        bf16x8 v2 = *(const bf16x8*)(src + 16);
        bf16x8 v3 = *(const bf16x8*)(src + 24);
        bf16_t* dst = &Vt[d * VTS + kc];
        *(bf16x8*)(dst)      = v0;
        *(bf16x8*)(dst + 8)  = v1;
        *(bf16x8*)(dst + 16) = v2;
        *(bf16x8*)(dst + 24) = v3;
      }
      __syncthreads();

      f32x4 s[2][8];
      for (int qi = 0; qi < 2; ++qi)
        for (int ki = 0; ki < 8; ++ki) s[qi][ki] = z4;
      for (int ks = 0; ks < 2; ++ks)
        for (int ki = 0; ki < 8; ++ki) {
          bf16x8 kf = *(const bf16x8*)&KL[ks * 4096 + (ki * 16 + fr) * 32 + quad * 8];
          s[0][ki] = mfma16(qf[0][ks], kf, s[0][ki]);
          s[1][ki] = mfma16(qf[1][ks], kf, s[1][ki]);
        }

      const float C2 = 0.18033688f;   // log2(e)/8
      const bool diag = (kt == qt);
      for (int hk = 0; hk < 2; ++hk) {
        for (int qi = 0; qi < 2; ++qi)
          for (int k2 = 0; k2 < 4; ++k2) {
            const int ki = hk * 4 + k2;
            for (int r = 0; r < 4; ++r) {
              float pe = fast_exp2(s[qi][ki][r] * C2);
              if (diag && (ki * 16 + fr > w * 32 + qi * 16 + quad * 4 + r))
                pe = 0.f;
              PP[(w * 32 + qi * 16 + quad * 4 + r) * PS + k2 * 16 + fr] =
                  (bf16_t)pe;
            }
          }
        for (int k2 = 0; k2 < 2; ++k2) {
          bf16x8 pf0 = *(const bf16x8*)&PP[(w * 32 + fr) * PS + k2 * 32 + quad * 8];
          bf16x8 pf1 = *(const bf16x8*)&PP[(w * 32 + 16 + fr) * PS + k2 * 32 + quad * 8];
          o_l[0] = mfma16(pf0, ones8, o_l[0]);
          o_l[1] = mfma16(pf1, ones8, o_l[1]);
          const int kb = hk * 64 + k2 * 32;
          for (int di = 0; di < 4; ++di) {
            bf16x8 vf = *(const bf16x8*)&Vt[(di * 16 + fr) * VTS + kb + quad * 8];
            o_acc[0][di] = mfma16(pf0, vf, o_acc[0][di]);
            o_acc[1][di] = mfma16(pf1, vf, o_acc[1][di]);
          }
        }
      }
      __syncthreads();
    }

    for (int qi = 0; qi < 2; ++qi)
      for (int r = 0; r < 4; ++r) {
        const float l  = __shfl(o_l[qi][r], lane & 48);
        const float rl = 1.f / l;
        const size_t qg_ = qbase + q0 + w * 32 + qi * 16 + quad * 4 + r;
        for (int di = 0; di < 4; ++di)
          O[qg_ * HID + h * HDIM + di * 16 + fr] = (bf16_t)(o_acc[qi][di][r] * rl);
      }
  }
}

extern "C" void kernel_launch(void* const* d_in, const int* in_sizes, int n_in,
                              void* d_out, int out_size, void* d_ws, size_t ws_size,
                              hipStream_t stream) {
  const float* x  = (const float*)d_in[0];
  // d_in[1] = causal mask (int32) -- recomputed inline, not read
  const float* Wq = (const float*)d_in[2];
  const float* bq = (const float*)d_in[3];
  const float* Wk = (const float*)d_in[4];
  const float* bk = (const float*)d_in[5];
  const float* Wv = (const float*)d_in[6];
  const float* bv = (const float*)d_in[7];
  const float* Wo = (const float*)d_in[8];
  const float* bo = (const float*)d_in[9];
  float* out = (float*)d_out;

  const size_t M = (size_t)NB * SLEN;          // 4096
  dim3 blk(256, 1, 1);

  const size_t needA = (M * HID
                        + (size_t)HID * HID
                        + (size_t)KVW * HID
                        + (size_t)KVW * HID
                        + (size_t)HID * HID
                        + M * HID
                        + M * KVW
                        + M * KVW) * 2
                       + (size_t)(HID + 2 * KVW) * sizeof(float);
  if (ws_size >= needA) {
    bf16_t* xb  = (bf16_t*)d_ws;
    bf16_t* Wqb = xb  + M * HID;              // Wq|Wk|Wv contiguous = Wcat
    bf16_t* Wkb = Wqb + (size_t)HID * HID;
    bf16_t* Wvb = Wkb + (size_t)KVW * HID;
    bf16_t* Wob = Wvb + (size_t)KVW * HID;
    bf16_t* Qb  = Wob + (size_t)HID * HID;
    bf16_t* Kb  = Qb  + M * HID;
    bf16_t* VbT = Kb  + M * KVW;
    float*  bcat = (float*)(VbT + M * KVW);   // [bq|bk|bv], 3072 floats

    cvt_kernel<<<dim3(1024, 5, 1), blk, 0, stream>>>(
        x, Wq, Wk, Wv, Wo, xb, Wqb, Wkb, Wvb, Wob);
    hipMemcpyAsync(bcat,             bq, HID * sizeof(float),
                   hipMemcpyDeviceToDevice, stream);
    hipMemcpyAsync(bcat + HID,       bk, KVW * sizeof(float),
                   hipMemcpyDeviceToDevice, stream);
    hipMemcpyAsync(bcat + HID + KVW, bv, KVW * sizeof(float),
                   hipMemcpyDeviceToDevice, stream);
    qkv8_kernel<<<dim3(12, 16, 1), dim3(512, 1, 1), 0, stream>>>(
        xb, Wqb, bcat, Qb, Kb, VbT);
    attn_kernel<<<dim3(8, 32, 2), blk, 0, stream>>>(Qb, Kb, VbT, Qb);
    oproj8_kernel<<<dim3(8, 16, 1), dim3(512, 1, 1), 0, stream>>>(
        Qb, Wob, bo, out);
  } else {
    bf16_t* Qb  = (bf16_t*)d_ws;
    bf16_t* Kb  = Qb + M * HID;
    bf16_t* Vb  = Kb + M * KVW;
    bf16_t* VbT = Vb + M * KVW;

    qkv_kernel<<<dim3(24, 32, 1), blk, 0, stream>>>(x, Wq, bq, Wk, bk, Wv, bv, Qb, Kb, Vb);
    vtrans_kernel<<<dim3(32, 8, 2), blk, 0, stream>>>(Vb, VbT);
    attn_kernel<<<dim3(8, 32, 2), blk, 0, stream>>>(Qb, Kb, VbT, Qb);
    oproj_kernel<<<dim3(16, 32, 1), blk, 0, stream>>>(Qb, Wo, bo, out);
  }
}

// Round 2
// 315.706 us; speedup vs baseline: 1.0293x; 1.0234x over previous
//
#include <hip/hip_runtime.h>
#include <hip/hip_bf16.h>
#include <stdint.h>

#define HID   2048
#define SLEN  2048
#define NB    2
#define NHEADS 32
#define NKVH   8
#define HDIM   64
#define KVW    512   // NKVH*HDIM

typedef __bf16 bf16_t;
typedef __bf16 bf16x2 __attribute__((ext_vector_type(2)));
typedef __bf16 bf16x4 __attribute__((ext_vector_type(4)));
typedef __bf16 bf16x8 __attribute__((ext_vector_type(8)));
typedef float  f32x4  __attribute__((ext_vector_type(4)));

__device__ __forceinline__ f32x4 mfma16(bf16x8 a, bf16x8 b, f32x4 c) {
  return __builtin_amdgcn_mfma_f32_16x16x32_bf16(a, b, c, 0, 0, 0);
}

__device__ __forceinline__ void gl2lds16(const bf16_t* g, bf16_t* l) {
  __builtin_amdgcn_global_load_lds(
      (const __attribute__((address_space(1))) void*)g,
      (__attribute__((address_space(3))) void*)l,
      16, 0, 0);
}

__device__ __forceinline__ float fast_exp2(float x) {
#if __has_builtin(__builtin_amdgcn_exp2f)
  return __builtin_amdgcn_exp2f(x);
#else
  return __expf(x * 0.69314718f);
#endif
}

__device__ __forceinline__ bf16x8 ld8(const bf16_t* p) {
  return *(const bf16x8*)p;
}
__device__ __forceinline__ bf16x8 ld8(const float* p) {
  f32x4 a = *(const f32x4*)p;
  f32x4 b = *(const f32x4*)(p + 4);
  bf16x8 r;
  r[0] = (bf16_t)a[0]; r[1] = (bf16_t)a[1]; r[2] = (bf16_t)a[2]; r[3] = (bf16_t)a[3];
  r[4] = (bf16_t)b[0]; r[5] = (bf16_t)b[1]; r[6] = (bf16_t)b[2]; r[7] = (bf16_t)b[3];
  return r;
}

__device__ __forceinline__ uint32_t pack2(float a, float b) {
  bf16x2 t; t[0] = (bf16_t)a; t[1] = (bf16_t)b;
  return __builtin_bit_cast(uint32_t, t);
}

__device__ __forceinline__ void st_c(bf16_t* p, float v) { *p = (bf16_t)v; }
__device__ __forceinline__ void st_c(float*  p, float v) { *p = v; }

// ---------------- fp32 -> bf16 convert pass + bias concat -------------------
__global__ __launch_bounds__(256) void cvt_kernel(
    const float* __restrict__ x,  const float* __restrict__ wq,
    const float* __restrict__ wk, const float* __restrict__ wv,
    const float* __restrict__ wo,
    const float* __restrict__ bq, const float* __restrict__ bk,
    const float* __restrict__ bv,
    bf16_t* xb, bf16_t* wqb, bf16_t* wkb, bf16_t* wvb, bf16_t* wob,
    float* bcat)
{
  if (blockIdx.y >= 5) {   // float->float bias concat
    const float* fs; float* fd; size_t n;
    if (blockIdx.y == 5)      { fs = bq; fd = bcat;        n = HID; }
    else if (blockIdx.y == 6) { fs = bk; fd = bcat + HID;  n = KVW; }
    else                      { fs = bv; fd = bcat + HID + KVW; n = KVW; }
    const size_t stride4 = (size_t)gridDim.x * 256 * 4;
    for (size_t i = ((size_t)blockIdx.x * 256 + threadIdx.x) * 4; i < n; i += stride4)
      *(f32x4*)(fd + i) = *(const f32x4*)(fs + i);
    return;
  }
  const float* s; bf16_t* d; size_t n;
  switch (blockIdx.y) {
    case 0:  s = x;  d = xb;  n = (size_t)NB * SLEN * HID; break;
    case 1:  s = wq; d = wqb; n = (size_t)HID * HID; break;
    case 2:  s = wk; d = wkb; n = (size_t)KVW * HID; break;
    case 3:  s = wv; d = wvb; n = (size_t)KVW * HID; break;
    default: s = wo; d = wob; n = (size_t)HID * HID; break;
  }
  const size_t stride = (size_t)gridDim.x * 256 * 8;
  for (size_t i = ((size_t)blockIdx.x * 256 + threadIdx.x) * 8; i < n; i += stride)
    *(bf16x8*)(d + i) = ld8(s + i);
}

// ====================== 256x256 8-phase GEMM (T2+T3+T4+T5) ==================
__device__ __forceinline__ bf16x8 ldfrag(const bf16_t* __restrict__ Lh, int r, int g) {
  return *(const bf16x8*)(Lh + r * 64 + ((g ^ (r & 7)) << 3));
}

template <int Q>
__device__ __forceinline__ void mfma_quad(const bf16x8 (&af)[2][2],
                                          const bf16x8 (&bfr)[4][2],
                                          f32x4 (&acc)[8][4]) {
#pragma unroll
  for (int ks = 0; ks < 2; ++ks)
#pragma unroll
    for (int i = 0; i < 2; ++i)
#pragma unroll
      for (int ni = 0; ni < 4; ++ni)
        acc[2 * Q + i][ni] = mfma16(af[i][ks], bfr[ni][ks], acc[2 * Q + i][ni]);
}

__device__ __forceinline__ void phase_barrier() {
  __builtin_amdgcn_s_barrier();
  asm volatile("" ::: "memory");
}

__device__ __forceinline__ void gemm256_core(
    const bf16_t* __restrict__ Ag,
    const bf16_t* __restrict__ Bg,
    bf16_t* __restrict__ lds, f32x4 (&acc)[8][4])
{
  const int tid  = threadIdx.x;
  const int lane = tid & 63;
  const int w    = tid >> 6;
  const int fr   = lane & 15;
  const int quad = lane >> 4;
  const int wr   = w >> 2;
  const int wc   = w & 3;
  const int rbB  = (wc & 1) * 64;

  bf16_t* A0 = lds;
  bf16_t* B0 = lds + 16384;
  bf16_t* A1 = lds + 32768;
  bf16_t* B1 = lds + 49152;
  const bf16_t* Ar0 = A0 + wr * 8192;
  const bf16_t* Br0 = B0 + (wc >> 1) * 8192;
  const bf16_t* Ar1 = A1 + wr * 8192;
  const bf16_t* Br1 = B1 + (wc >> 1) * 8192;

  const f32x4 z4 = {0.f, 0.f, 0.f, 0.f};
#pragma unroll
  for (int i = 0; i < 8; ++i)
#pragma unroll
    for (int j = 0; j < 4; ++j) acc[i][j] = z4;

  auto STAGE = [&](const bf16_t* __restrict__ Gp, bf16_t* __restrict__ Lh) {
#pragma unroll
    for (int j = 0; j < 2; ++j) {
      const int s = j * 512 + tid;
      const int r = s >> 3;
      const int g = (s & 7) ^ (r & 7);
      gl2lds16(Gp + (size_t)r * HID + g * 8, Lh + s * 8);
    }
  };

  STAGE(Bg,                  B0);
  STAGE(Bg + 128 * HID,      B0 + 8192);
  STAGE(Ag,                  A0);
  STAGE(Ag + 128 * HID,      A0 + 8192);
  STAGE(Bg + 64,             B1);
  STAGE(Bg + 128 * HID + 64, B1 + 8192);
  asm volatile("s_waitcnt vmcnt(4)" ::: "memory");
  phase_barrier();

  bf16x8 bfr[4][2], af[2][2];

#pragma unroll 1
  for (int it = 0; it < 16; ++it) {
    const bool more = (it < 15);
    const size_t k1 = (size_t)(2 * it + 1) * 64;
    const size_t k2 = (size_t)(2 * it + 2) * 64;
    const size_t k3 = (size_t)(2 * it + 3) * 64;

#pragma unroll
    for (int ni = 0; ni < 4; ++ni)
#pragma unroll
      for (int ks = 0; ks < 2; ++ks)
        bfr[ni][ks] = ldfrag(Br0, rbB + ni * 16 + fr, ks * 4 + quad);
#pragma unroll
    for (int i = 0; i < 2; ++i)
#pragma unroll
      for (int ks = 0; ks < 2; ++ks)
        af[i][ks] = ldfrag(Ar0, i * 16 + fr, ks * 4 + quad);
    STAGE(Ag + k1, A1);
    phase_barrier();
    asm volatile("s_waitcnt lgkmcnt(0)" ::: "memory");
    __builtin_amdgcn_s_setprio(1);
    mfma_quad<0>(af, bfr, acc);
    __builtin_amdgcn_s_setprio(0);
    phase_barrier();

#pragma unroll
    for (int i = 0; i < 2; ++i)
#pragma unroll
      for (int ks = 0; ks < 2; ++ks)
        af[i][ks] = ldfrag(Ar0, 32 + i * 16 + fr, ks * 4 + quad);
    STAGE(Ag + 128 * HID + k1, A1 + 8192);
    phase_barrier();
    asm volatile("s_waitcnt lgkmcnt(0)" ::: "memory");
    __builtin_amdgcn_s_setprio(1);
    mfma_quad<1>(af, bfr, acc);
    __builtin_amdgcn_s_setprio(0);
    phase_barrier();

#pragma unroll
    for (int i = 0; i < 2; ++i)
#pragma unroll
      for (int ks = 0; ks < 2; ++ks)
        af[i][ks] = ldfrag(Ar0, 64 + i * 16 + fr, ks * 4 + quad);
    if (more) STAGE(Bg + k2, B0);
    phase_barrier();
    asm volatile("s_waitcnt lgkmcnt(0)" ::: "memory");
    __builtin_amdgcn_s_setprio(1);
    mfma_quad<2>(af, bfr, acc);
    __builtin_amdgcn_s_setprio(0);
    phase_barrier();

#pragma unroll
    for (int i = 0; i < 2; ++i)
#pragma unroll
      for (int ks = 0; ks < 2; ++ks)
        af[i][ks] = ldfrag(Ar0, 96 + i * 16 + fr, ks * 4 + quad);
    if (more) STAGE(Bg + 128 * HID + k2, B0 + 8192);
    phase_barrier();
    asm volatile("s_waitcnt lgkmcnt(0)" ::: "memory");
    __builtin_amdgcn_s_setprio(1);
    mfma_quad<3>(af, bfr, acc);
    __builtin_amdgcn_s_setprio(0);
    if (more) { asm volatile("s_waitcnt vmcnt(4)" ::: "memory"); }
    else      { asm volatile("s_waitcnt vmcnt(0)" ::: "memory"); }
    phase_barrier();

#pragma unroll
    for (int ni = 0; ni < 4; ++ni)
#pragma unroll
      for (int ks = 0; ks < 2; ++ks)
        bfr[ni][ks] = ldfrag(Br1, rbB + ni * 16 + fr, ks * 4 + quad);
#pragma unroll
    for (int i = 0; i < 2; ++i)
#pragma unroll
      for (int ks = 0; ks < 2; ++ks)
        af[i][ks] = ldfrag(Ar1, i * 16 + fr, ks * 4 + quad);
    if (more) STAGE(Ag + k2, A0);
    phase_barrier();
    asm volatile("s_waitcnt lgkmcnt(0)" ::: "memory");
    __builtin_amdgcn_s_setprio(1);
    mfma_quad<0>(af, bfr, acc);
    __builtin_amdgcn_s_setprio(0);
    phase_barrier();

#pragma unroll
    for (int i = 0; i < 2; ++i)
#pragma unroll
      for (int ks = 0; ks < 2; ++ks)
        af[i][ks] = ldfrag(Ar1, 32 + i * 16 + fr, ks * 4 + quad);
    if (more) STAGE(Ag + 128 * HID + k2, A0 + 8192);
    phase_barrier();
    asm volatile("s_waitcnt lgkmcnt(0)" ::: "memory");
    __builtin_amdgcn_s_setprio(1);
    mfma_quad<1>(af, bfr, acc);
    __builtin_amdgcn_s_setprio(0);
    phase_barrier();

#pragma unroll
    for (int i = 0; i < 2; ++i)
#pragma unroll
      for (int ks = 0; ks < 2; ++ks)
        af[i][ks] = ldfrag(Ar1, 64 + i * 16 + fr, ks * 4 + quad);
    if (more) STAGE(Bg + k3, B1);
    phase_barrier();
    asm volatile("s_waitcnt lgkmcnt(0)" ::: "memory");
    __builtin_amdgcn_s_setprio(1);
    mfma_quad<2>(af, bfr, acc);
    __builtin_amdgcn_s_setprio(0);
    phase_barrier();

#pragma unroll
    for (int i = 0; i < 2; ++i)
#pragma unroll
      for (int ks = 0; ks < 2; ++ks)
        af[i][ks] = ldfrag(Ar1, 96 + i * 16 + fr, ks * 4 + quad);
    if (more) STAGE(Bg + 128 * HID + k3, B1 + 8192);
    phase_barrier();
    asm volatile("s_waitcnt lgkmcnt(0)" ::: "memory");
    __builtin_amdgcn_s_setprio(1);
    mfma_quad<3>(af, bfr, acc);
    __builtin_amdgcn_s_setprio(0);
    if (more) { asm volatile("s_waitcnt vmcnt(4)" ::: "memory"); }
    phase_barrier();
  }
}

__global__ __launch_bounds__(512, 2) void qkv8_kernel(
    const bf16_t* __restrict__ xb, const bf16_t* __restrict__ Wcat,
    const float* __restrict__ bcat,
    bf16_t* __restrict__ Qb, bf16_t* __restrict__ Kb, bf16_t* __restrict__ VbT)
{
  __shared__ __align__(16) bf16_t lds[65536];
  const int cb = blockIdx.x;   // 0..11
  const int mb = blockIdx.y;   // 0..15
  f32x4 acc[8][4];
  gemm256_core(xb + (size_t)mb * 256 * HID, Wcat + (size_t)cb * 256 * HID, lds, acc);

  const int tid = threadIdx.x, lane = tid & 63, w = tid >> 6;
  const int fr = lane & 15, quad = lane >> 4, wr = w >> 2, wc = w & 3;
#pragma unroll
  for (int ni = 0; ni < 4; ++ni) {
    const int gcol = cb * 256 + wc * 64 + ni * 16 + fr;
    const float bz = bcat[gcol];
#pragma unroll
    for (int mi = 0; mi < 8; ++mi) {
      const int grow = mb * 256 + wr * 128 + mi * 16 + quad * 4;
      if (cb < 8) {
#pragma unroll
        for (int r = 0; r < 4; ++r)
          Qb[(size_t)(grow + r) * HID + gcol] = (bf16_t)(acc[mi][ni][r] + bz);
      } else if (cb < 10) {
        const int kc = gcol - 2048;
#pragma unroll
        for (int r = 0; r < 4; ++r)
          Kb[(size_t)(grow + r) * KVW + kc] = (bf16_t)(acc[mi][ni][r] + bz);
      } else {
        const int vc = gcol - 2560;
        const int b = grow >> 11, s = grow & 2047;
        bf16x4 pk;
#pragma unroll
        for (int r = 0; r < 4; ++r) pk[r] = (bf16_t)(acc[mi][ni][r] + bz);
        *(bf16x4*)&VbT[((size_t)(b * NKVH + (vc >> 6)) * HDIM + (vc & 63)) * SLEN + s] = pk;
      }
    }
  }
}

__global__ __launch_bounds__(512, 2) void oproj8_kernel(
    const bf16_t* __restrict__ A, const bf16_t* __restrict__ Wob,
    const float* __restrict__ bo, float* __restrict__ out)
{
  __shared__ __align__(16) bf16_t lds[65536];
  const int cb = blockIdx.x;
  const int mb = blockIdx.y;
  f32x4 acc[8][4];
  gemm256_core(A + (size_t)mb * 256 * HID, Wob + (size_t)cb * 256 * HID, lds, acc);

  const int tid = threadIdx.x, lane = tid & 63, w = tid >> 6;
  const int fr = lane & 15, quad = lane >> 4, wr = w >> 2, wc = w & 3;
#pragma unroll
  for (int ni = 0; ni < 4; ++ni) {
    const int gcol = cb * 256 + wc * 64 + ni * 16 + fr;
    const float bz = bo[gcol];
#pragma unroll
    for (int mi = 0; mi < 8; ++mi) {
      const int grow = mb * 256 + wr * 128 + mi * 16 + quad * 4;
#pragma unroll
      for (int r = 0; r < 4; ++r)
        out[(size_t)(grow + r) * HID + gcol] = acc[mi][ni][r] + bz;
    }
  }
}

// ---------------- Path B (fallback): fp32-source GEMM -----------------------
template <typename AT, typename CT>
__device__ __forceinline__ void gemm128_tile(
    const AT* __restrict__ Ap, int lda,
    const float* __restrict__ Wp, int ldw,
    const float* __restrict__ biasp,
    CT* __restrict__ Cp, int ldc,
    int K)
{
  __shared__ __align__(16) bf16_t Al[128 * 32];
  __shared__ __align__(16) bf16_t Bl[128 * 32];

  const int tid  = threadIdx.x;
  const int lane = tid & 63;
  const int w    = tid >> 6;
  const int fr   = lane & 15;
  const int quad = lane >> 4;
  const int wm   = (w >> 1) * 64;
  const int wn   = (w & 1) * 64;

  const f32x4 z4 = {0.f, 0.f, 0.f, 0.f};
  f32x4 acc[4][4];
  for (int i = 0; i < 4; ++i)
    for (int j = 0; j < 4; ++j) acc[i][j] = z4;

  const int c0    = w * 2;
  const int srow0 = lane >> 2;
  const int skc   = (lane & 3) * 8;

  for (int k0 = 0; k0 < K; k0 += 32) {
    bf16x8 av[2], bv[2];
    for (int t = 0; t < 2; ++t) {
      const int r = (c0 + t) * 16 + srow0;
      av[t] = ld8(Ap + (size_t)r * lda + k0 + skc);
      bv[t] = ld8(Wp + (size_t)r * ldw + k0 + skc);
    }
    for (int t = 0; t < 2; ++t) {
      const int c = c0 + t;
      *(bf16x8*)&Al[c * 512 + lane * 8] = av[t];
      *(bf16x8*)&Bl[c * 512 + lane * 8] = bv[t];
    }
    __syncthreads();
    bf16x8 af[4], bfr[4];
    for (int mi = 0; mi < 4; ++mi)
      af[mi] = *(const bf16x8*)&Al[(wm + mi * 16 + fr) * 32 + quad * 8];
    for (int ni = 0; ni < 4; ++ni)
      bfr[ni] = *(const bf16x8*)&Bl[(wn + ni * 16 + fr) * 32 + quad * 8];
    for (int mi = 0; mi < 4; ++mi)
      for (int ni = 0; ni < 4; ++ni)
        acc[mi][ni] = mfma16(af[mi], bfr[ni], acc[mi][ni]);
    __syncthreads();
  }

  for (int ni = 0; ni < 4; ++ni) {
    const int col = wn + ni * 16 + fr;
    const float bz = biasp[col];
    for (int mi = 0; mi < 4; ++mi) {
      const int r0 = wm + mi * 16 + quad * 4;
      for (int r = 0; r < 4; ++r)
        st_c(Cp + (size_t)(r0 + r) * ldc + col, acc[mi][ni][r] + bz);
    }
  }
}

__global__ __launch_bounds__(256) void qkv_kernel(
    const float* __restrict__ x,
    const float* __restrict__ Wq, const float* __restrict__ bq,
    const float* __restrict__ Wk, const float* __restrict__ bk,
    const float* __restrict__ Wv, const float* __restrict__ bv,
    bf16_t* Qb, bf16_t* Kb, bf16_t* Vb)
{
  const int nb = blockIdx.x;
  const int mb = blockIdx.y;
  const float* W; const float* bias; bf16_t* C; int ldc;
  if (nb < 16)      { W = Wq + (size_t)nb * 128 * HID;  bias = bq + nb * 128;
                      C = Qb + nb * 128; ldc = HID; }
  else if (nb < 20) { const int j = nb - 16;
                      W = Wk + (size_t)j * 128 * HID;   bias = bk + j * 128;
                      C = Kb + j * 128; ldc = KVW; }
  else              { const int j = nb - 20;
                      W = Wv + (size_t)j * 128 * HID;   bias = bv + j * 128;
                      C = Vb + j * 128; ldc = KVW; }
  gemm128_tile<float, bf16_t>(x + (size_t)mb * 128 * HID, HID, W, HID, bias,
                              C + (size_t)mb * 128 * ldc, ldc, HID);
}

__global__ __launch_bounds__(256) void oproj_kernel(
    const bf16_t* __restrict__ A, const float* __restrict__ Wo,
    const float* __restrict__ bo, float* out)
{
  const int nb = blockIdx.x, mb = blockIdx.y;
  gemm128_tile<bf16_t, float>(A + (size_t)mb * 128 * HID, HID,
                              Wo + (size_t)nb * 128 * HID, HID,
                              bo + nb * 128,
                              out + (size_t)mb * 128 * HID + nb * 128, HID, HID);
}

__global__ __launch_bounds__(256) void vtrans_kernel(
    const bf16_t* __restrict__ Vb, bf16_t* __restrict__ VbT)
{
  __shared__ bf16_t T[64][72];
  const int st = blockIdx.x, kvh = blockIdx.y, b = blockIdx.z;
  const int tid = threadIdx.x;
  {
    const int row = tid >> 2;
    const int c16 = (tid & 3) * 16;
    const bf16_t* src =
        Vb + ((size_t)b * SLEN + st * 64 + row) * KVW + kvh * HDIM + c16;
    *(bf16x8*)&T[row][c16]     = *(const bf16x8*)(src);
    *(bf16x8*)&T[row][c16 + 8] = *(const bf16x8*)(src + 8);
  }
  __syncthreads();
  {
    const int d  = tid >> 2;
    const int sc = (tid & 3) * 16;
    bf16_t tmp[16];
    for (int j = 0; j < 16; ++j) tmp[j] = T[sc + j][d];
    bf16_t* dst = VbT + ((size_t)(b * NKVH + kvh) * HDIM + d) * SLEN + st * 64 + sc;
    *(bf16x8*)dst       = *(bf16x8*)&tmp[0];
    *(bf16x8*)(dst + 8) = *(bf16x8*)&tmp[8];
  }
}

// ---------------- Flash attention: swapped QK^T, in-register P --------------
// 4 waves, QBLK=64 (16 q-rows per wave), KVBLK=128. Grid (16, 32, 2).
// QK^T computed as mfma(K, Q): lane holds P[q = fr][k = ki*16 + quad*4 + r].
// PV A-fragments built in-register: pack bf16 pairs + one shfl_xor(16)
// exchange; the residual quad1<->quad2 permutation is absorbed by reading V
// with sigma(quad)*8 k-offsets (k-relabeling of the contraction is free as
// long as both operands use it). No P through LDS; no bank conflicts.
__global__ __launch_bounds__(256, 4) void attn_kernel(
    const bf16_t* Q, const bf16_t* __restrict__ Kg,
    const bf16_t* __restrict__ VT, bf16_t* O)
{
  const int pid = blockIdx.x;        // 0..15
  const int h   = blockIdx.y;
  const int b   = blockIdx.z;
  const int kvh = h >> 2;

  const int tid  = threadIdx.x;
  const int lane = tid & 63;
  const int w    = tid >> 6;         // 0..3
  const int fr   = lane & 15;
  const int quad = lane >> 4;

  __shared__ __align__(16) bf16_t KL[8192];    // [ks(2)][krow(128)][32]
  __shared__ __align__(16) bf16_t VtL[8192];   // [kb(4)][d(64)][32]

  const size_t qbase = (size_t)b * SLEN;
  const bf16_t* VTh = VT + (size_t)(b * NKVH + kvh) * HDIM * SLEN;

  // sigma: 0->0, 1->2, 2->1, 3->3 (units of 8 elements)
  const int sigma8 = ((quad & 1) << 4) | ((quad & 2) << 2);
  const bool oddq = (quad & 1);

  bf16x8 ones8;
  {
    const bf16_t o1 = (bf16_t)(fr == 0 ? 1.0f : 0.0f);
#pragma unroll
    for (int j = 0; j < 8; ++j) ones8[j] = o1;
  }

  for (int half = 0; half < 2; ++half) {
    const int qt = half ? (31 - pid) : pid;
    const int q0 = qt * 64;

    bf16x8 qf[2];
#pragma unroll
    for (int ks = 0; ks < 2; ++ks)
      qf[ks] = *(const bf16x8*)&Q[(qbase + q0 + w * 16 + fr) * HID
                                  + h * HDIM + ks * 32 + quad * 8];

    const f32x4 z4 = {0.f, 0.f, 0.f, 0.f};
    f32x4 o_acc[4];
    f32x4 o_l = z4;
#pragma unroll
    for (int di = 0; di < 4; ++di) o_acc[di] = z4;

    const int ktmax = qt >> 1;
    const int qloc  = (qt & 1) * 64 + w * 16 + fr;   // q local to diag tile

    for (int kt = 0; kt <= ktmax; ++kt) {
      const size_t krow0 = qbase + (size_t)kt * 128;

      // stage K: element (ks,kr,c) at KL[ks*4096 + kr*32 + c]
#pragma unroll
      for (int j = 0; j < 4; ++j) {
        const int s  = j * 256 + tid;
        const int ks = s >> 9, kr = (s >> 2) & 127, c8 = s & 3;
        gl2lds16(&Kg[(krow0 + kr) * KVW + kvh * HDIM + ks * 32 + c8 * 8],
                 &KL[s * 8]);
      }
      // stage V^T: element (kb,d,c) at VtL[kb*2048 + d*32 + c]
#pragma unroll
      for (int j = 0; j < 4; ++j) {
        const int idx = j * 256 + tid;
        const int kb = idx >> 8, d = (idx >> 2) & 63, c8 = idx & 3;
        gl2lds16(&VTh[(size_t)d * SLEN + kt * 128 + kb * 32 + c8 * 8],
                 &VtL[idx * 8]);
      }
      __syncthreads();

      // QK^T swapped: s8[ki] rows = k (quad*4+r), cols = q (fr)
      f32x4 s8[8];
#pragma unroll
      for (int ki = 0; ki < 8; ++ki) s8[ki] = z4;
#pragma unroll
      for (int ks = 0; ks < 2; ++ks)
#pragma unroll
        for (int ki = 0; ki < 8; ++ki) {
          bf16x8 kf = *(const bf16x8*)&KL[ks * 4096 + (ki * 16 + fr) * 32 + quad * 8];
          s8[ki] = mfma16(kf, qf[ks], s8[ki]);
        }

      const float C2 = 0.18033688f;   // log2(e)/8
      const bool diag = (kt == ktmax);

#pragma unroll
      for (int m = 0; m < 4; ++m) {
        float pe[8];
#pragma unroll
        for (int ki2 = 0; ki2 < 2; ++ki2) {
          const int ki = 2 * m + ki2;
#pragma unroll
          for (int r = 0; r < 4; ++r) {
            float p = fast_exp2(s8[ki][r] * C2);
            if (diag && (ki * 16 + quad * 4 + r > qloc)) p = 0.f;
            pe[ki2 * 4 + r] = p;
          }
        }
        // pack pairs: w0..w3 hold k = 32m + quad*4+{0,1},{2,3},16+{0,1},16+{2,3}
        uint32_t pw0 = pack2(pe[0], pe[1]);
        uint32_t pw1 = pack2(pe[2], pe[3]);
        uint32_t pw2 = pack2(pe[4], pe[5]);
        uint32_t pw3 = pack2(pe[6], pe[7]);
        // exchange with quad^1 partner: even sends w2/w3, odd sends w0/w1
        uint32_t x0 = oddq ? pw0 : pw2;
        uint32_t x1 = oddq ? pw1 : pw3;
        uint32_t r0 = (uint32_t)__shfl_xor((int)x0, 16);
        uint32_t r1 = (uint32_t)__shfl_xor((int)x1, 16);
        union { uint32_t u[4]; bf16x8 v; } pb;
        pb.u[0] = oddq ? r0 : pw0;
        pb.u[1] = oddq ? r1 : pw1;
        pb.u[2] = oddq ? pw2 : r0;
        pb.u[3] = oddq ? pw3 : r1;

        o_l = mfma16(pb.v, ones8, o_l);
#pragma unroll
        for (int di = 0; di < 4; ++di) {
          bf16x8 vf = *(const bf16x8*)&VtL[m * 2048 + (di * 16 + fr) * 32 + sigma8];
          o_acc[di] = mfma16(pb.v, vf, o_acc[di]);
        }
      }
      __syncthreads();
    }

    // epilogue: o_acc rows = q (quad*4+r), cols = d (di*16+fr); l at fr==0
#pragma unroll
    for (int r = 0; r < 4; ++r) {
      const float l  = __shfl(o_l[r], lane & 48);
      const float rl = 1.f / l;
      const size_t qg = qbase + q0 + w * 16 + quad * 4 + r;
#pragma unroll
      for (int di = 0; di < 4; ++di)
        O[qg * HID + h * HDIM + di * 16 + fr] = (bf16_t)(o_acc[di][r] * rl);
    }
  }
}

extern "C" void kernel_launch(void* const* d_in, const int* in_sizes, int n_in,
                              void* d_out, int out_size, void* d_ws, size_t ws_size,
                              hipStream_t stream) {
  const float* x  = (const float*)d_in[0];
  // d_in[1] = causal mask (int32) -- recomputed inline, not read
  const float* Wq = (const float*)d_in[2];
  const float* bq = (const float*)d_in[3];
  const float* Wk = (const float*)d_in[4];
  const float* bk = (const float*)d_in[5];
  const float* Wv = (const float*)d_in[6];
  const float* bv = (const float*)d_in[7];
  const float* Wo = (const float*)d_in[8];
  const float* bo = (const float*)d_in[9];
  float* out = (float*)d_out;

  const size_t M = (size_t)NB * SLEN;          // 4096
  dim3 blk(256, 1, 1);

  const size_t needA = (M * HID
                        + (size_t)HID * HID
                        + (size_t)KVW * HID
                        + (size_t)KVW * HID
                        + (size_t)HID * HID
                        + M * HID
                        + M * KVW
                        + M * KVW) * 2
                       + (size_t)(HID + 2 * KVW) * sizeof(float);
  if (ws_size >= needA) {
    bf16_t* xb  = (bf16_t*)d_ws;
    bf16_t* Wqb = xb  + M * HID;              // Wq|Wk|Wv contiguous = Wcat
    bf16_t* Wkb = Wqb + (size_t)HID * HID;
    bf16_t* Wvb = Wkb + (size_t)KVW * HID;
    bf16_t* Wob = Wvb + (size_t)KVW * HID;
    bf16_t* Qb  = Wob + (size_t)HID * HID;
    bf16_t* Kb  = Qb  + M * HID;
    bf16_t* VbT = Kb  + M * KVW;
    float*  bcat = (float*)(VbT + M * KVW);   // [bq|bk|bv], 3072 floats

    cvt_kernel<<<dim3(1024, 8, 1), blk, 0, stream>>>(
        x, Wq, Wk, Wv, Wo, bq, bk, bv, xb, Wqb, Wkb, Wvb, Wob, bcat);
    qkv8_kernel<<<dim3(12, 16, 1), dim3(512, 1, 1), 0, stream>>>(
        xb, Wqb, bcat, Qb, Kb, VbT);
    attn_kernel<<<dim3(16, 32, 2), blk, 0, stream>>>(Qb, Kb, VbT, Qb);
    oproj8_kernel<<<dim3(8, 16, 1), dim3(512, 1, 1), 0, stream>>>(
        Qb, Wob, bo, out);
  } else {
    bf16_t* Qb  = (bf16_t*)d_ws;
    bf16_t* Kb  = Qb + M * HID;
    bf16_t* Vb  = Kb + M * KVW;
    bf16_t* VbT = Vb + M * KVW;

    qkv_kernel<<<dim3(24, 32, 1), blk, 0, stream>>>(x, Wq, bq, Wk, bk, Wv, bv, Qb, Kb, Vb);
    vtrans_kernel<<<dim3(32, 8, 2), blk, 0, stream>>>(Vb, VbT);
    attn_kernel<<<dim3(16, 32, 2), blk, 0, stream>>>(Qb, Kb, VbT, Qb);
    oproj_kernel<<<dim3(16, 32, 1), blk, 0, stream>>>(Qb, Wo, bo, out);
  }
}